// Round 6
// baseline (315.891 us; speedup 1.0000x reference)
//
#include <hip/hip_runtime.h>
#include <stdint.h>

#define NCOMP 5
#define DM 1024
#define LN_EPS 1e-5f

typedef __attribute__((ext_vector_type(8))) __bf16 bf16x8;
typedef __attribute__((ext_vector_type(4))) float f32x4;

__device__ __forceinline__ unsigned short f2bf(float f) {
    unsigned u = __builtin_bit_cast(unsigned, f);
    u += 0x7fffu + ((u >> 16) & 1u);   // round-to-nearest-even
    return (unsigned short)(u >> 16);
}

// -------- kernel 1: fused compartment LayerNorm + (W+I)->bf16 --------
// PERSISTENT grid-stride kernel (2048 blocks): each wave loops over ~4
// units, TWO independent units per iteration (dual dependency chains hide
// the shfl-reduce serial section + load latency under each other). One
// wave per unit, no LDS, no barriers; lane owns 8 consecutive elements ->
// float4 x2 loads (32 B/lane) and uint4 stores (16 B/lane, full 1KB/instr).
__device__ __forceinline__ void ln_unit(
    int t, int lane, int M,
    const float* __restrict__ x, const int* __restrict__ cid,
    const float* __restrict__ gamma, const float* __restrict__ beta,
    const float* __restrict__ scale, const float* __restrict__ W,
    unsigned short* __restrict__ y, unsigned short* __restrict__ Wb)
{
    if (t < M) {
        const int e0 = lane * 8;            // elems [e0, e0+7] and [e0+512, ...]
        const float* xp = x + (size_t)t * DM;
        float4 a0 = *(const float4*)(xp + e0);
        float4 a1 = *(const float4*)(xp + e0 + 4);
        float4 b0 = *(const float4*)(xp + 512 + e0);
        float4 b1 = *(const float4*)(xp + 512 + e0 + 4);
        const int craw = cid[t];            // no deps: issues immediately

        float s  = a0.x + a0.y + a0.z + a0.w + a1.x + a1.y + a1.z + a1.w
                 + b0.x + b0.y + b0.z + b0.w + b1.x + b1.y + b1.z + b1.w;
        float ss = a0.x*a0.x + a0.y*a0.y + a0.z*a0.z + a0.w*a0.w
                 + a1.x*a1.x + a1.y*a1.y + a1.z*a1.z + a1.w*a1.w
                 + b0.x*b0.x + b0.y*b0.y + b0.z*b0.z + b0.w*b0.w
                 + b1.x*b1.x + b1.y*b1.y + b1.z*b1.z + b1.w*b1.w;
#pragma unroll
        for (int off = 32; off; off >>= 1) {   // 64-lane butterfly
            s  += __shfl_xor(s, off);
            ss += __shfl_xor(ss, off);
        }
        const float mu  = s * (1.0f / DM);
        const float var = ss * (1.0f / DM) - mu * mu;
        const float rs  = rsqrtf(var + LN_EPS);

        const bool valid = craw < NCOMP;    // reference guard
        const int c = min(max(craw, 0), NCOMP - 1);
        const float sc = scale[c];
        const float* gp = gamma + (size_t)c * DM;
        const float* bp = beta  + (size_t)c * DM;
        unsigned short* yp = y + (size_t)t * DM;
#pragma unroll
        for (int h = 0; h < 2; ++h) {
            const int e = h * 512 + e0;
            const float4 va = h ? b0 : a0;
            const float4 vb = h ? b1 : a1;
            const float4 g0 = *(const float4*)(gp + e);
            const float4 g1 = *(const float4*)(gp + e + 4);
            const float4 t0 = *(const float4*)(bp + e);
            const float4 t1 = *(const float4*)(bp + e + 4);
            float o[8];
            o[0] = valid ? ((va.x - mu) * rs * g0.x + t0.x) * sc : va.x;
            o[1] = valid ? ((va.y - mu) * rs * g0.y + t0.y) * sc : va.y;
            o[2] = valid ? ((va.z - mu) * rs * g0.z + t0.z) * sc : va.z;
            o[3] = valid ? ((va.w - mu) * rs * g0.w + t0.w) * sc : va.w;
            o[4] = valid ? ((vb.x - mu) * rs * g1.x + t1.x) * sc : vb.x;
            o[5] = valid ? ((vb.y - mu) * rs * g1.y + t1.y) * sc : vb.y;
            o[6] = valid ? ((vb.z - mu) * rs * g1.z + t1.z) * sc : vb.z;
            o[7] = valid ? ((vb.w - mu) * rs * g1.w + t1.w) * sc : vb.w;
            uint4 p;
            p.x = (unsigned)f2bf(o[0]) | ((unsigned)f2bf(o[1]) << 16);
            p.y = (unsigned)f2bf(o[2]) | ((unsigned)f2bf(o[3]) << 16);
            p.z = (unsigned)f2bf(o[4]) | ((unsigned)f2bf(o[5]) << 16);
            p.w = (unsigned)f2bf(o[6]) | ((unsigned)f2bf(o[7]) << 16);
            *(uint4*)(yp + e) = p;
        }
    } else {
        const int row = t - M;              // 0..DM-1
        const float* wp = W + (size_t)row * DM;
        unsigned short* wo = Wb + (size_t)row * DM;
#pragma unroll
        for (int h = 0; h < 2; ++h) {
            const int e = h * 512 + lane * 8;
            float4 a = *(const float4*)(wp + e);
            float4 b = *(const float4*)(wp + e + 4);
            // fold identity: out = y*(W+I)^T + b
            a.x += (e + 0 == row) ? 1.0f : 0.0f;
            a.y += (e + 1 == row) ? 1.0f : 0.0f;
            a.z += (e + 2 == row) ? 1.0f : 0.0f;
            a.w += (e + 3 == row) ? 1.0f : 0.0f;
            b.x += (e + 4 == row) ? 1.0f : 0.0f;
            b.y += (e + 5 == row) ? 1.0f : 0.0f;
            b.z += (e + 6 == row) ? 1.0f : 0.0f;
            b.w += (e + 7 == row) ? 1.0f : 0.0f;
            uint4 p;
            p.x = (unsigned)f2bf(a.x) | ((unsigned)f2bf(a.y) << 16);
            p.y = (unsigned)f2bf(a.z) | ((unsigned)f2bf(a.w) << 16);
            p.z = (unsigned)f2bf(b.x) | ((unsigned)f2bf(b.y) << 16);
            p.w = (unsigned)f2bf(b.z) | ((unsigned)f2bf(b.w) << 16);
            *(uint4*)(wo + e) = p;
        }
    }
}

__global__ __launch_bounds__(256) void ln_w_kernel(
    const float* __restrict__ x, const int* __restrict__ cid,
    const float* __restrict__ gamma, const float* __restrict__ beta,
    const float* __restrict__ scale, const float* __restrict__ W,
    unsigned short* __restrict__ y, unsigned short* __restrict__ Wb, int M)
{
    const int lane  = threadIdx.x & 63;
    const int w     = blockIdx.x * 4 + (threadIdx.x >> 6);  // global wave id
    const int nw    = gridDim.x * 4;
    const int total = M + DM;
    // two independent units per iteration -> dual chains, 2x ILP
    for (int t0 = w * 2; t0 < total; t0 += 2 * nw) {
        ln_unit(t0, lane, M, x, cid, gamma, beta, scale, W, y, Wb);
        if (t0 + 1 < total)
            ln_unit(t0 + 1, lane, M, x, cid, gamma, beta, scale, W, y, Wb);
    }
}

// -------- kernel 2: C = A * Bp^T + bias (Bp = W + I, bf16) --------
// (FROZEN from R5 for attribution.)
// 256x256 tile, BK=32, quad-buffered LDS, 8 waves (2Mx4N), per-wave 128x64.
// FULL register double-buffering: ALL 12 fragments (afA,afB,bfr) of tile
// t+1 are read inside tile t's MFMA shadows. One s_barrier per K-tile.
__device__ __forceinline__ void gld16(const unsigned short* g, unsigned short* l) {
    __builtin_amdgcn_global_load_lds(
        (const __attribute__((address_space(1))) unsigned int*)(uintptr_t)g,
        (__attribute__((address_space(3))) unsigned int*)(uintptr_t)l,
        16, 0, 0);
}

#define GEMM_ITER(T, CA, CAB, CB, NA, NAB, NB)                                \
  {                                                                           \
    const int t_ = (T);                                                       \
    /* MFMA-A: acc[0..3] on current regs (read during iter t-1) */            \
    __builtin_amdgcn_s_setprio(1);                                            \
    _Pragma("unroll")                                                         \
    for (int j = 0; j < 4; ++j)                                               \
        _Pragma("unroll")                                                     \
        for (int n = 0; n < 4; ++n)                                           \
            acc[j][n] = __builtin_amdgcn_mfma_f32_16x16x32_bf16(              \
                CB[n], CA[j], acc[j][n], 0, 0, 0);                            \
    __builtin_amdgcn_s_setprio(0);                                            \
    /* stage tile t+3 (buf (t+3)&3 == (t-1)&3) */                             \
    if (t_ < 29) {                                                            \
        unsigned short* stg = smem + ((t_ + 3) & 3) * BUF;                    \
        const int kn = (t_ + 3) * 32;                                         \
        gld16(gA0 + kn, stg + sA0);                                           \
        gld16(gA1 + kn, stg + sA1);                                           \
        gld16(gB0 + kn, stg + sB0);                                           \
        gld16(gB1 + kn, stg + sB1);                                           \
    }                                                                         \
    /* counted wait: own tile-(t+1) loads landed; t+2,t+3 stay in flight */   \
    if (t_ < 29)       { asm volatile("s_waitcnt vmcnt(8)" ::: "memory"); }   \
    else if (t_ == 29) { asm volatile("s_waitcnt vmcnt(4)" ::: "memory"); }   \
    else               { asm volatile("s_waitcnt vmcnt(0)" ::: "memory"); }   \
    __builtin_amdgcn_s_barrier();   /* ALL waves' tile t+1 now in LDS */      \
    /* next-tile B + A-low fragments; overlap with MFMA-B below */            \
    if (t_ < 31) {                                                            \
        const unsigned short* An = smem + ((t_ + 1) & 3) * BUF;               \
        const unsigned short* Bn = An + 8192;                                 \
        _Pragma("unroll")                                                     \
        for (int j = 0; j < 4; ++j)                                           \
            NB[j] = *(const bf16x8*)&Bn[(wn + j * 16) * 32 + loff];           \
        _Pragma("unroll")                                                     \
        for (int j = 0; j < 4; ++j)                                           \
            NA[j] = *(const bf16x8*)&An[(wm + j * 16) * 32 + loff];           \
    }                                                                         \
    /* MFMA-B: acc[4..7], zero lgkm dependency (all regs current) */          \
    __builtin_amdgcn_s_setprio(1);                                            \
    _Pragma("unroll")                                                         \
    for (int j = 0; j < 4; ++j)                                               \
        _Pragma("unroll")                                                     \
        for (int n = 0; n < 4; ++n)                                           \
            acc[4 + j][n] = __builtin_amdgcn_mfma_f32_16x16x32_bf16(          \
                CB[n], CAB[j], acc[4 + j][n], 0, 0, 0);                       \
    __builtin_amdgcn_s_setprio(0);                                            \
    /* next-tile A-high fragments; hidden under next iter's MFMA-A */         \
    if (t_ < 31) {                                                            \
        const unsigned short* An = smem + ((t_ + 1) & 3) * BUF;               \
        _Pragma("unroll")                                                     \
        for (int j = 0; j < 4; ++j)                                           \
            NAB[j] = *(const bf16x8*)&An[(wm + 64 + j * 16) * 32 + loff];     \
    }                                                                         \
  }

__global__ __launch_bounds__(512, 2) void gemm_kernel(
    const unsigned short* __restrict__ A,
    const unsigned short* __restrict__ Bp,
    const float* __restrict__ bias,
    float* __restrict__ C, int M)
{
    constexpr int K = 1024, N = 1024;
    constexpr int BUF = 16384;                    // shorts per buffer: A 8192 + B 8192
    __shared__ __align__(16) unsigned short smem[4 * BUF];   // 128 KiB

    const int tid  = threadIdx.x;
    const int lane = tid & 63;
    const int wave = tid >> 6;
    const int wm   = (wave >> 2) * 128;           // 2 M-wave-groups
    const int wn   = (wave & 3) * 64;             // 4 N-wave-groups

    // T1: XCD-aware block swizzle (nwg = 512, divisible by 8 -> bijective)
    const int nwg = gridDim.x;
    int wg = blockIdx.x;
    if ((nwg & 7) == 0) wg = (wg & 7) * (nwg >> 3) + (wg >> 3);
    const int bm = (wg >> 2) * 256;               // n fastest -> A-panel L2 reuse
    const int bn = (wg & 3) * 256;

    // ---- staging addressing (T2: linear LDS dest + pre-swizzled global src) ----
    const int qsrc = (((lane & 3) ^ ((lane >> 3) & 3))) * 8;  // element offset
    const int rA0  = (wave * 2) * 16 + (lane >> 2);
    const unsigned short* gA0 = A  + (size_t)(bm + rA0) * K + qsrc;
    const unsigned short* gA1 = A  + (size_t)(bm + rA0 + 16) * K + qsrc;
    const unsigned short* gB0 = Bp + (size_t)(bn + rA0) * K + qsrc;
    const unsigned short* gB1 = Bp + (size_t)(bn + rA0 + 16) * K + qsrc;
    const int sA0 = (wave * 2) * 512 + lane * 8;  // shorts within buf (linear)
    const int sA1 = sA0 + 512;
    const int sB0 = 8192 + sA0;
    const int sB1 = 8192 + sA1;

    // ---- fragment read offset (swizzled): 2-way bank aliasing = free ----
    const int fr   = lane & 15;
    const int quad = lane >> 4;
    const int loff = fr * 32 + ((quad ^ ((fr >> 1) & 3)) * 8);

    f32x4 acc[8][4] = {};

    // prologue: stage K-tiles 0,1,2 (12 loads/thread in flight)
#pragma unroll
    for (int kt = 0; kt < 3; ++kt) {
        unsigned short* sb = smem + kt * BUF;
        gld16(gA0 + kt * 32, sb + sA0);
        gld16(gA1 + kt * 32, sb + sA1);
        gld16(gB0 + kt * 32, sb + sB0);
        gld16(gB1 + kt * 32, sb + sB1);
    }
    asm volatile("s_waitcnt vmcnt(8)" ::: "memory");  // own tile-0 loads landed
    __builtin_amdgcn_s_barrier();                     // all waves' tile 0 in LDS

    bf16x8 afA0[4], afB0[4], bfr0[4], afA1[4], afB1[4], bfr1[4];
    {   // initial fragments: ALL of tile 0
        const unsigned short* A0 = smem;
        const unsigned short* B0 = smem + 8192;
#pragma unroll
        for (int j = 0; j < 4; ++j)
            bfr0[j] = *(const bf16x8*)&B0[(wn + j * 16) * 32 + loff];
#pragma unroll
        for (int j = 0; j < 4; ++j)
            afA0[j] = *(const bf16x8*)&A0[(wm + j * 16) * 32 + loff];
#pragma unroll
        for (int j = 0; j < 4; ++j)
            afB0[j] = *(const bf16x8*)&A0[(wm + 64 + j * 16) * 32 + loff];
    }

    for (int t = 0; t < 32; t += 2) {
        GEMM_ITER(t,     afA0, afB0, bfr0, afA1, afB1, bfr1)
        GEMM_ITER(t + 1, afA1, afB1, bfr1, afA0, afB0, bfr0)
    }

    // ---- epilogue: vectorized per-wave LDS transpose -> full 128B lines ----
    // Swapped-operand C/D layout: acc[mi][ni] reg r = C[wm+mi*16+fr][wn+ni*16+quad*4+r].
    // ds_write_b128 (2-way, free) -> ds_read_b128 (2-way) -> 256B/row stores.
    float* tb = (float*)smem + wave * 1088;   // 16 rows x 68 floats, per-wave private
    const int q4 = quad * 4;
    const float4 bvT = *(const float4*)&bias[bn + wn + fr * 4];
#pragma unroll
    for (int mi = 0; mi < 8; ++mi) {
#pragma unroll
        for (int ni = 0; ni < 4; ++ni)
            *(float4*)&tb[fr * 68 + ni * 16 + q4] = *(const float4*)&acc[mi][ni];
        // same-wave LDS: in-order pipe + compiler lgkmcnt waits; no barrier
#pragma unroll
        for (int j = 0; j < 4; ++j) {
            const int row = j * 4 + quad;
            const float4 v = *(const float4*)&tb[row * 68 + fr * 4];
            float4 o;
            o.x = v.x + bvT.x; o.y = v.y + bvT.y;
            o.z = v.z + bvT.z; o.w = v.w + bvT.w;
            *(float4*)&C[(size_t)(bm + wm + mi * 16 + row) * N + bn + wn + fr * 4] = o;
        }
    }
}

extern "C" void kernel_launch(void* const* d_in, const int* in_sizes, int n_in,
                              void* d_out, int out_size, void* d_ws, size_t ws_size,
                              hipStream_t stream)
{
    const float* x     = (const float*)d_in[0];
    const int*   cid   = (const int*)d_in[1];
    const float* gamma = (const float*)d_in[2];
    const float* beta  = (const float*)d_in[3];
    const float* scale = (const float*)d_in[4];
    const float* W     = (const float*)d_in[5];
    const float* bias  = (const float*)d_in[6];
    float* out = (float*)d_out;

    const int M = in_sizes[0] / DM;                        // 32768 tokens
    unsigned short* yb = (unsigned short*)d_ws;            // M*1024 bf16 = 64 MB
    unsigned short* Wb = yb + (size_t)M * DM;              // 1024*1024 bf16 = 2 MB

    // persistent: 2048 blocks x 4 waves, 2 units per wave per iteration
    ln_w_kernel<<<2048, 256, 0, stream>>>(x, cid, gamma, beta, scale, W, yb, Wb, M);
    gemm_kernel<<<dim3((M / 256) * 4), 512, 0, stream>>>(yb, Wb, bias, out, M);
}

// Round 7
// 312.111 us; speedup vs baseline: 1.0121x; 1.0121x over previous
//
#include <hip/hip_runtime.h>
#include <stdint.h>

#define NCOMP 5
#define DM 1024
#define LN_EPS 1e-5f

typedef __attribute__((ext_vector_type(8))) __bf16 bf16x8;
typedef __attribute__((ext_vector_type(4))) float f32x4;

__device__ __forceinline__ unsigned short f2bf(float f) {
    unsigned u = __builtin_bit_cast(unsigned, f);
    u += 0x7fffu + ((u >> 16) & 1u);   // round-to-nearest-even
    return (unsigned short)(u >> 16);
}

// -------- kernel 1: fused compartment LayerNorm + (W+I)->bf16 --------
// (REVERTED to the R5 one-shot version: best measured ~64-67 us.
//  R6's persistent grid-stride variant regressed to ~76.)
// ONE WAVE PER TOKEN: no LDS, no __syncthreads, reduction = 6 shfl_xor
// butterflies. 256-thread blocks = 4 independent waves = 4 units.
__global__ __launch_bounds__(256) void ln_w_kernel(
    const float* __restrict__ x, const int* __restrict__ cid,
    const float* __restrict__ gamma, const float* __restrict__ beta,
    const float* __restrict__ scale, const float* __restrict__ W,
    unsigned short* __restrict__ y, unsigned short* __restrict__ Wb, int M)
{
    const int lane = threadIdx.x & 63;
    const int t = blockIdx.x * 4 + (threadIdx.x >> 6);   // wave-uniform unit id

    if (t < M) {
        const float* xp = x + (size_t)t * DM;
        float4 v[4];
#pragma unroll
        for (int q = 0; q < 4; ++q)
            v[q] = *(const float4*)(xp + q * 256 + lane * 4);

        float s = 0.f, ss = 0.f;
#pragma unroll
        for (int q = 0; q < 4; ++q) {
            s  += v[q].x + v[q].y + v[q].z + v[q].w;
            ss += v[q].x*v[q].x + v[q].y*v[q].y + v[q].z*v[q].z + v[q].w*v[q].w;
        }
#pragma unroll
        for (int off = 32; off; off >>= 1) {   // 64-lane butterfly
            s  += __shfl_xor(s, off);
            ss += __shfl_xor(ss, off);
        }
        const float mu  = s * (1.0f / DM);
        const float var = ss * (1.0f / DM) - mu * mu;
        const float rs  = rsqrtf(var + LN_EPS);

        const int craw  = cid[t];
        const bool valid = craw < NCOMP;       // reference guard
        const int c = min(max(craw, 0), NCOMP - 1);
        const float sc = scale[c];
        const float* gp = gamma + (size_t)c * DM;
        const float* bp = beta  + (size_t)c * DM;
        unsigned short* yp = y + (size_t)t * DM;
#pragma unroll
        for (int q = 0; q < 4; ++q) {
            const int e = q * 256 + lane * 4;
            const float4 g  = *(const float4*)(gp + e);
            const float4 bb = *(const float4*)(bp + e);
            const float o0 = valid ? ((v[q].x - mu) * rs * g.x + bb.x) * sc : v[q].x;
            const float o1 = valid ? ((v[q].y - mu) * rs * g.y + bb.y) * sc : v[q].y;
            const float o2 = valid ? ((v[q].z - mu) * rs * g.z + bb.z) * sc : v[q].z;
            const float o3 = valid ? ((v[q].w - mu) * rs * g.w + bb.w) * sc : v[q].w;
            uint2 p;
            p.x = (unsigned)f2bf(o0) | ((unsigned)f2bf(o1) << 16);
            p.y = (unsigned)f2bf(o2) | ((unsigned)f2bf(o3) << 16);
            *(uint2*)(yp + e) = p;
        }
    } else if (t < M + DM) {
        const int row = t - M;                 // 0..DM-1
        const float* wp = W + (size_t)row * DM;
        unsigned short* wo = Wb + (size_t)row * DM;
#pragma unroll
        for (int q = 0; q < 4; ++q) {
            const int e = q * 256 + lane * 4;
            float4 a = *(const float4*)(wp + e);
            // fold identity: out = y*(W+I)^T + b
            a.x += (e + 0 == row) ? 1.0f : 0.0f;
            a.y += (e + 1 == row) ? 1.0f : 0.0f;
            a.z += (e + 2 == row) ? 1.0f : 0.0f;
            a.w += (e + 3 == row) ? 1.0f : 0.0f;
            uint2 p;
            p.x = (unsigned)f2bf(a.x) | ((unsigned)f2bf(a.y) << 16);
            p.y = (unsigned)f2bf(a.z) | ((unsigned)f2bf(a.w) << 16);
            *(uint2*)(wo + e) = p;
        }
    }
}

// -------- kernel 2: C = A * Bp^T + bias (Bp = W + I, bf16) --------
// PERSISTENT 2-PANEL version: grid 256 blocks; block X computes output
// panels wgeff = X and X+256. The quad-buffer counted-vmcnt pipeline NEVER
// drains across the panel boundary: p0 iters t=29..31 stage p1 tiles 0..2
// (bufs 0..2 -- exactly the steady rotation), t=31's read slot loads p1's
// initial fragments (overlapped with MFMA-B), and p1's K-loop continues
// with the identical vmcnt(8) ledger. Epilogue scratch lives in buf3
// (dead after t31's barrier); one barrier separates epilogue-0 from p1's
// t0 staging into buf3.
// Hazard ledger unchanged from R5 steady state: stage into buf b only >=1
// barrier after b's last frag read; reads of a staged tile only after
// vmcnt(8)+barrier two tiles later.
__device__ __forceinline__ void gld16(const unsigned short* g, unsigned short* l) {
    __builtin_amdgcn_global_load_lds(
        (const __attribute__((address_space(1))) unsigned int*)(uintptr_t)g,
        (__attribute__((address_space(3))) unsigned int*)(uintptr_t)l,
        16, 0, 0);
}

// MODE 0: more panels follow -> tail stages NEXT panel's tiles, vmcnt(8)
//         always, reads at t=31 fetch next panel's tile-0 fragments.
// MODE 1: last panel -> stages stop at t<29, vmcnt drains 8->4->0,
//         reads guarded t<31.
#define GEMM_ITER(T, MODE, CA, CAB, CB, NA, NAB, NB)                          \
  {                                                                           \
    const int t_ = (T);                                                       \
    /* MFMA-A: acc[0..3] on current regs (read during iter t-1) */            \
    __builtin_amdgcn_s_setprio(1);                                            \
    _Pragma("unroll")                                                         \
    for (int j = 0; j < 4; ++j)                                               \
        _Pragma("unroll")                                                     \
        for (int n = 0; n < 4; ++n)                                           \
            acc[j][n] = __builtin_amdgcn_mfma_f32_16x16x32_bf16(              \
                CB[n], CA[j], acc[j][n], 0, 0, 0);                            \
    __builtin_amdgcn_s_setprio(0);                                            \
    /* stage tile t+3 (buf (t+3)&3; old data last read before prev barrier)*/ \
    if (t_ < 29) {                                                            \
        unsigned short* stg = smem + ((t_ + 3) & 3) * BUF;                    \
        const int kn = (t_ + 3) * 32;                                         \
        gld16(gA0 + kn, stg + sA0);                                           \
        gld16(gA1 + kn, stg + sA1);                                           \
        gld16(gB0 + kn, stg + sB0);                                           \
        gld16(gB1 + kn, stg + sB1);                                           \
    } else if (MODE == 0) {                                                   \
        /* seamless: stage NEXT panel's tile (t-29) into buf (t+3)&3 */       \
        unsigned short* stg = smem + ((t_ + 3) & 3) * BUF;                    \
        const int kn2 = (t_ - 29) * 32;                                       \
        gld16(gA0 + kn2 + dA, stg + sA0);                                     \
        gld16(gA1 + kn2 + dA, stg + sA1);                                     \
        gld16(gB0 + kn2 + dB, stg + sB0);                                     \
        gld16(gB1 + kn2 + dB, stg + sB1);                                     \
    }                                                                         \
    /* counted wait: tile-(t+1) loads landed; 2 tiles stay in flight */       \
    if (MODE == 0 || t_ < 29) { asm volatile("s_waitcnt vmcnt(8)" ::: "memory"); } \
    else if (t_ == 29)        { asm volatile("s_waitcnt vmcnt(4)" ::: "memory"); } \
    else                      { asm volatile("s_waitcnt vmcnt(0)" ::: "memory"); } \
    __builtin_amdgcn_s_barrier();   /* ALL waves' tile t+1 now in LDS */      \
    /* next-tile B + A-low fragments; overlap with MFMA-B below.  For */      \
    /* MODE 0 at t=31 this reads NEXT panel's tile 0 (buf 0, landed). */      \
    if (MODE == 0 || t_ < 31) {                                               \
        const unsigned short* An = smem + ((t_ + 1) & 3) * BUF;               \
        const unsigned short* Bn = An + 8192;                                 \
        _Pragma("unroll")                                                     \
        for (int j = 0; j < 4; ++j)                                           \
            NB[j] = *(const bf16x8*)&Bn[(wn + j * 16) * 32 + loff];           \
        _Pragma("unroll")                                                     \
        for (int j = 0; j < 4; ++j)                                           \
            NA[j] = *(const bf16x8*)&An[(wm + j * 16) * 32 + loff];           \
    }                                                                         \
    /* MFMA-B: acc[4..7], zero lgkm dependency (all regs current) */          \
    __builtin_amdgcn_s_setprio(1);                                            \
    _Pragma("unroll")                                                         \
    for (int j = 0; j < 4; ++j)                                               \
        _Pragma("unroll")                                                     \
        for (int n = 0; n < 4; ++n)                                           \
            acc[4 + j][n] = __builtin_amdgcn_mfma_f32_16x16x32_bf16(          \
                CB[n], CAB[j], acc[4 + j][n], 0, 0, 0);                       \
    __builtin_amdgcn_s_setprio(0);                                            \
    /* next-tile A-high fragments; hidden under next iter's MFMA-A */         \
    if (MODE == 0 || t_ < 31) {                                               \
        const unsigned short* An = smem + ((t_ + 1) & 3) * BUF;               \
        _Pragma("unroll")                                                     \
        for (int j = 0; j < 4; ++j)                                           \
            NAB[j] = *(const bf16x8*)&An[(wm + 64 + j * 16) * 32 + loff];     \
    }                                                                         \
  }

// Epilogue: per-wave XOR-swizzled scratch in buf3 (32 KB total, 4 KB/wave).
// Writer lane (quad,fr) stores acc[mi][ni] = C[row=fr][16B-block ni*4+quad]
// at physical slot (ni*4+quad) ^ ((fr&7)<<1); reader of (row, block fr)
// uses slot fr ^ ((row&7)<<1). Both access patterns are bank-uniform
// (8 lanes per 4-bank group = conflict-free for b128).
#define EPILOGUE()                                                            \
  {                                                                           \
    float* tb = (float*)(smem + 3 * BUF) + wave * 1024;                       \
    const float4 bvT = *(const float4*)&bias[bn + wn + fr * 4];               \
    _Pragma("unroll")                                                         \
    for (int mi = 0; mi < 8; ++mi) {                                          \
        _Pragma("unroll")                                                     \
        for (int ni = 0; ni < 4; ++ni)                                        \
            *(float4*)&tb[fr * 64 + (((ni * 4 + quad) ^ ((fr & 7) << 1)) * 4)]\
                = *(const float4*)&acc[mi][ni];                               \
        _Pragma("unroll")                                                     \
        for (int j = 0; j < 4; ++j) {                                         \
            const int row = j * 4 + quad;                                     \
            const float4 v = *(const float4*)                                 \
                &tb[row * 64 + ((fr ^ ((row & 7) << 1)) * 4)];                \
            float4 o;                                                         \
            o.x = v.x + bvT.x; o.y = v.y + bvT.y;                             \
            o.z = v.z + bvT.z; o.w = v.w + bvT.w;                             \
            *(float4*)&C[(size_t)(bm + wm + mi * 16 + row) * N                \
                         + bn + wn + fr * 4] = o;                             \
        }                                                                     \
    }                                                                         \
  }

__global__ __launch_bounds__(512, 2) void gemm_kernel(
    const unsigned short* __restrict__ A,
    const unsigned short* __restrict__ Bp,
    const float* __restrict__ bias,
    float* __restrict__ C, int M)
{
    constexpr int K = 1024, N = 1024;
    constexpr int BUF = 16384;                    // shorts per buffer: A 8192 + B 8192
    __shared__ __align__(16) unsigned short smem[4 * BUF];   // 128 KiB

    const int tid  = threadIdx.x;
    const int lane = tid & 63;
    const int wave = tid >> 6;
    const int wm   = (wave >> 2) * 128;           // 2 M-wave-groups
    const int wn   = (wave & 3) * 64;             // 4 N-wave-groups

    // T1: XCD swizzle over the FULL logical grid (nwg=512, 8|nwg -> bijective).
    // Block X runs wgeff = X (panel 0) and X+256 (panel 1); both map to the
    // same XCD chunk as the original 512-block launch -> L2 locality kept.
    const int nwg = gridDim.x * 2;
    const int wge0 = blockIdx.x;
    const int wge1 = blockIdx.x + gridDim.x;
    const int wg0 = (wge0 & 7) * (nwg >> 3) + (wge0 >> 3);
    const int wg1 = (wge1 & 7) * (nwg >> 3) + (wge1 >> 3);
    const int bm0 = (wg0 >> 2) * 256, bn0 = (wg0 & 3) * 256;
    const int bm1 = (wg1 >> 2) * 256, bn1 = (wg1 & 3) * 256;
    // next-panel deltas (element units, wave-uniform)
    const ptrdiff_t dA = (ptrdiff_t)(bm1 - bm0) * K;
    const ptrdiff_t dB = (ptrdiff_t)(bn1 - bn0) * K;

    int bm = bm0, bn = bn0;

    // ---- staging addressing (T2: linear LDS dest + pre-swizzled global src) ----
    const int qsrc = (((lane & 3) ^ ((lane >> 3) & 3))) * 8;  // element offset
    const int rA0  = (wave * 2) * 16 + (lane >> 2);
    const unsigned short* gA0 = A  + (size_t)(bm + rA0) * K + qsrc;
    const unsigned short* gA1 = A  + (size_t)(bm + rA0 + 16) * K + qsrc;
    const unsigned short* gB0 = Bp + (size_t)(bn + rA0) * K + qsrc;
    const unsigned short* gB1 = Bp + (size_t)(bn + rA0 + 16) * K + qsrc;
    const int sA0 = (wave * 2) * 512 + lane * 8;  // shorts within buf (linear)
    const int sA1 = sA0 + 512;
    const int sB0 = 8192 + sA0;
    const int sB1 = 8192 + sA1;

    // ---- fragment read offset (swizzled): 2-way bank aliasing = free ----
    const int fr   = lane & 15;
    const int quad = lane >> 4;
    const int loff = fr * 32 + ((quad ^ ((fr >> 1) & 3)) * 8);

    const f32x4 fzero = {0.f, 0.f, 0.f, 0.f};
    f32x4 acc[8][4] = {};

    // prologue: stage K-tiles 0,1,2 of panel 0 (12 loads/thread in flight)
#pragma unroll
    for (int kt = 0; kt < 3; ++kt) {
        unsigned short* sb = smem + kt * BUF;
        gld16(gA0 + kt * 32, sb + sA0);
        gld16(gA1 + kt * 32, sb + sA1);
        gld16(gB0 + kt * 32, sb + sB0);
        gld16(gB1 + kt * 32, sb + sB1);
    }
    asm volatile("s_waitcnt vmcnt(8)" ::: "memory");  // own tile-0 loads landed
    __builtin_amdgcn_s_barrier();                     // all waves' tile 0 in LDS

    bf16x8 afA0[4], afB0[4], bfr0[4], afA1[4], afB1[4], bfr1[4];
    {   // initial fragments: ALL of panel-0 tile 0
        const unsigned short* A0 = smem;
        const unsigned short* B0 = smem + 8192;
#pragma unroll
        for (int j = 0; j < 4; ++j)
            bfr0[j] = *(const bf16x8*)&B0[(wn + j * 16) * 32 + loff];
#pragma unroll
        for (int j = 0; j < 4; ++j)
            afA0[j] = *(const bf16x8*)&A0[(wm + j * 16) * 32 + loff];
#pragma unroll
        for (int j = 0; j < 4; ++j)
            afB0[j] = *(const bf16x8*)&A0[(wm + 64 + j * 16) * 32 + loff];
    }

    // ================= panel 0 K-loop (MODE 0: seamless tail) =================
    for (int t = 0; t < 32; t += 2) {
        GEMM_ITER(t,     0, afA0, afB0, bfr0, afA1, afB1, bfr1)
        GEMM_ITER(t + 1, 0, afA1, afB1, bfr1, afA0, afB0, bfr0)
    }
    // t=31 already loaded panel-1 tile-0 fragments into set0 (buf 0).

    // ---- panel-0 epilogue (scratch = buf3; its last frag reads finished ----
    // ---- before t31's barrier, which every wave has passed)             ----
    EPILOGUE()
    // all waves done with buf3 scratch before panel-1 t0 stages into buf3
    __builtin_amdgcn_s_barrier();

    // ================= panel 1 =================
    bm = bm1; bn = bn1;
    gA0 += dA; gA1 += dA; gB0 += dB; gB1 += dB;
#pragma unroll
    for (int j = 0; j < 8; ++j)
#pragma unroll
        for (int n = 0; n < 4; ++n)
            acc[j][n] = fzero;

    for (int t = 0; t < 32; t += 2) {
        GEMM_ITER(t,     1, afA0, afB0, bfr0, afA1, afB1, bfr1)
        GEMM_ITER(t + 1, 1, afA1, afB1, bfr1, afA0, afB0, bfr0)
    }

    // ---- panel-1 epilogue (buf3 again; same ledger) ----
    EPILOGUE()
}

extern "C" void kernel_launch(void* const* d_in, const int* in_sizes, int n_in,
                              void* d_out, int out_size, void* d_ws, size_t ws_size,
                              hipStream_t stream)
{
    const float* x     = (const float*)d_in[0];
    const int*   cid   = (const int*)d_in[1];
    const float* gamma = (const float*)d_in[2];
    const float* beta  = (const float*)d_in[3];
    const float* scale = (const float*)d_in[4];
    const float* W     = (const float*)d_in[5];
    const float* bias  = (const float*)d_in[6];
    float* out = (float*)d_out;

    const int M = in_sizes[0] / DM;                        // 32768 tokens
    unsigned short* yb = (unsigned short*)d_ws;            // M*1024 bf16 = 64 MB
    unsigned short* Wb = yb + (size_t)M * DM;              // 1024*1024 bf16 = 2 MB

    // one wave per unit: (M + DM) units, 4 waves per 256-thread block
    ln_w_kernel<<<(M + DM) / 4, 256, 0, stream>>>(x, cid, gamma, beta, scale, W, yb, Wb, M);
    // persistent: 256 blocks x 2 panels (logical grid 512)
    gemm_kernel<<<dim3((M / 256) * 4 / 2), 512, 0, stream>>>(yb, Wb, bias, out, M);
}

// Round 8
// 304.213 us; speedup vs baseline: 1.0384x; 1.0260x over previous
//
#include <hip/hip_runtime.h>
#include <stdint.h>

#define NCOMP 5
#define DM 1024
#define LN_EPS 1e-5f

typedef __attribute__((ext_vector_type(8))) __bf16 bf16x8;
typedef __attribute__((ext_vector_type(4))) float f32x4;

// gfx950 HW packed f32->bf16 convert (RNE). No builtin on gfx950 (m240):
// inline asm. dst.lo = cvt(lo), dst.hi = cvt(hi).
__device__ __forceinline__ unsigned cvt_pk_bf16(float lo, float hi) {
    unsigned r;
    asm("v_cvt_pk_bf16_f32 %0, %1, %2" : "=v"(r) : "v"(lo), "v"(hi));
    return r;
}

// -------- kernel 1: fused compartment LayerNorm + (W+I)->bf16 --------
// ONE WAVE PER TOKEN (one-shot launch, best-measured structure R4/R5):
// no LDS, no __syncthreads, 6-step shfl_xor butterfly reduce.
// This round: (1) wave-uniform `valid` branch replaces 16 per-element
// cndmasks (cid is uniform per wave); (2) v_cvt_pk_bf16_f32 replaces the
// 6-op manual RNE pack (16 elems: 8 instrs vs ~48); (3) gamma/beta loads
// issued BEFORE the butterfly (depend only on cid) so L2 latency hides
// under the reduce.
__global__ __launch_bounds__(256) void ln_w_kernel(
    const float* __restrict__ x, const int* __restrict__ cid,
    const float* __restrict__ gamma, const float* __restrict__ beta,
    const float* __restrict__ scale, const float* __restrict__ W,
    unsigned short* __restrict__ y, unsigned short* __restrict__ Wb, int M)
{
    const int lane = threadIdx.x & 63;
    const int t = blockIdx.x * 4 + (threadIdx.x >> 6);   // wave-uniform unit id

    if (t < M) {
        const float* xp = x + (size_t)t * DM;
        float4 v[4];
#pragma unroll
        for (int q = 0; q < 4; ++q)
            v[q] = *(const float4*)(xp + q * 256 + lane * 4);

        const int craw = cid[t];
        const bool valid = craw < NCOMP;       // wave-uniform reference guard
        unsigned short* yp = y + (size_t)t * DM;

        if (valid) {
            const int c = min(max(craw, 0), NCOMP - 1);
            const float sc = scale[c];
            const float* gp = gamma + (size_t)c * DM;
            const float* bp = beta  + (size_t)c * DM;
            // issue g/b loads now; latency overlaps the butterfly below
            float4 g[4], bb[4];
#pragma unroll
            for (int q = 0; q < 4; ++q) {
                const int e = q * 256 + lane * 4;
                g[q]  = *(const float4*)(gp + e);
                bb[q] = *(const float4*)(bp + e);
            }

            float s = 0.f, ss = 0.f;
#pragma unroll
            for (int q = 0; q < 4; ++q) {
                s  += v[q].x + v[q].y + v[q].z + v[q].w;
                ss += v[q].x*v[q].x + v[q].y*v[q].y + v[q].z*v[q].z + v[q].w*v[q].w;
            }
#pragma unroll
            for (int off = 32; off; off >>= 1) {   // 64-lane butterfly
                s  += __shfl_xor(s, off);
                ss += __shfl_xor(ss, off);
            }
            const float mu  = s * (1.0f / DM);
            const float var = ss * (1.0f / DM) - mu * mu;
            const float rs  = rsqrtf(var + LN_EPS);

#pragma unroll
            for (int q = 0; q < 4; ++q) {
                const int e = q * 256 + lane * 4;
                const float o0 = ((v[q].x - mu) * rs * g[q].x + bb[q].x) * sc;
                const float o1 = ((v[q].y - mu) * rs * g[q].y + bb[q].y) * sc;
                const float o2 = ((v[q].z - mu) * rs * g[q].z + bb[q].z) * sc;
                const float o3 = ((v[q].w - mu) * rs * g[q].w + bb[q].w) * sc;
                uint2 p;
                p.x = cvt_pk_bf16(o0, o1);
                p.y = cvt_pk_bf16(o2, o3);
                *(uint2*)(yp + e) = p;
            }
        } else {
            // untouched token: y = x (bf16). No reduce, no g/b needed.
#pragma unroll
            for (int q = 0; q < 4; ++q) {
                const int e = q * 256 + lane * 4;
                uint2 p;
                p.x = cvt_pk_bf16(v[q].x, v[q].y);
                p.y = cvt_pk_bf16(v[q].z, v[q].w);
                *(uint2*)(yp + e) = p;
            }
        }
    } else if (t < M + DM) {
        const int row = t - M;                 // 0..DM-1
        const float* wp = W + (size_t)row * DM;
        unsigned short* wo = Wb + (size_t)row * DM;
#pragma unroll
        for (int q = 0; q < 4; ++q) {
            const int e = q * 256 + lane * 4;
            float4 a = *(const float4*)(wp + e);
            // fold identity: out = y*(W+I)^T + b
            a.x += (e + 0 == row) ? 1.0f : 0.0f;
            a.y += (e + 1 == row) ? 1.0f : 0.0f;
            a.z += (e + 2 == row) ? 1.0f : 0.0f;
            a.w += (e + 3 == row) ? 1.0f : 0.0f;
            uint2 p;
            p.x = cvt_pk_bf16(a.x, a.y);
            p.y = cvt_pk_bf16(a.z, a.w);
            *(uint2*)(wo + e) = p;
        }
    }
}

// -------- kernel 2: C = A * Bp^T + bias (Bp = W + I, bf16) --------
// (REVERTED byte-for-byte to the R5 version -- best measured 79.5-80.1 us.
//  R7's persistent 2-panel variant regressed: FETCH 49->56 MB, WRITE
//  131->141 MB, epilogue-swizzle conflicts 2x.)
// 256x256 tile, BK=32, quad-buffered LDS, 8 waves (2Mx4N), per-wave 128x64.
// FULL register double-buffering: ALL 12 fragments (afA,afB,bfr) of tile
// t+1 are read inside tile t's MFMA shadows. One s_barrier per K-tile.
__device__ __forceinline__ void gld16(const unsigned short* g, unsigned short* l) {
    __builtin_amdgcn_global_load_lds(
        (const __attribute__((address_space(1))) unsigned int*)(uintptr_t)g,
        (__attribute__((address_space(3))) unsigned int*)(uintptr_t)l,
        16, 0, 0);
}

#define GEMM_ITER(T, CA, CAB, CB, NA, NAB, NB)                                \
  {                                                                           \
    const int t_ = (T);                                                       \
    /* MFMA-A: acc[0..3] on current regs (read during iter t-1) */            \
    __builtin_amdgcn_s_setprio(1);                                            \
    _Pragma("unroll")                                                         \
    for (int j = 0; j < 4; ++j)                                               \
        _Pragma("unroll")                                                     \
        for (int n = 0; n < 4; ++n)                                           \
            acc[j][n] = __builtin_amdgcn_mfma_f32_16x16x32_bf16(              \
                CB[n], CA[j], acc[j][n], 0, 0, 0);                            \
    __builtin_amdgcn_s_setprio(0);                                            \
    /* stage tile t+3 (buf (t+3)&3 == (t-1)&3) */                             \
    if (t_ < 29) {                                                            \
        unsigned short* stg = smem + ((t_ + 3) & 3) * BUF;                    \
        const int kn = (t_ + 3) * 32;                                         \
        gld16(gA0 + kn, stg + sA0);                                           \
        gld16(gA1 + kn, stg + sA1);                                           \
        gld16(gB0 + kn, stg + sB0);                                           \
        gld16(gB1 + kn, stg + sB1);                                           \
    }                                                                         \
    /* counted wait: own tile-(t+1) loads landed; t+2,t+3 stay in flight */   \
    if (t_ < 29)       { asm volatile("s_waitcnt vmcnt(8)" ::: "memory"); }   \
    else if (t_ == 29) { asm volatile("s_waitcnt vmcnt(4)" ::: "memory"); }   \
    else               { asm volatile("s_waitcnt vmcnt(0)" ::: "memory"); }   \
    __builtin_amdgcn_s_barrier();   /* ALL waves' tile t+1 now in LDS */      \
    /* next-tile B + A-low fragments; overlap with MFMA-B below */            \
    if (t_ < 31) {                                                            \
        const unsigned short* An = smem + ((t_ + 1) & 3) * BUF;               \
        const unsigned short* Bn = An + 8192;                                 \
        _Pragma("unroll")                                                     \
        for (int j = 0; j < 4; ++j)                                           \
            NB[j] = *(const bf16x8*)&Bn[(wn + j * 16) * 32 + loff];           \
        _Pragma("unroll")                                                     \
        for (int j = 0; j < 4; ++j)                                           \
            NA[j] = *(const bf16x8*)&An[(wm + j * 16) * 32 + loff];           \
    }                                                                         \
    /* MFMA-B: acc[4..7], zero lgkm dependency (all regs current) */          \
    __builtin_amdgcn_s_setprio(1);                                            \
    _Pragma("unroll")                                                         \
    for (int j = 0; j < 4; ++j)                                               \
        _Pragma("unroll")                                                     \
        for (int n = 0; n < 4; ++n)                                           \
            acc[4 + j][n] = __builtin_amdgcn_mfma_f32_16x16x32_bf16(          \
                CB[n], CAB[j], acc[4 + j][n], 0, 0, 0);                       \
    __builtin_amdgcn_s_setprio(0);                                            \
    /* next-tile A-high fragments; hidden under next iter's MFMA-A */         \
    if (t_ < 31) {                                                            \
        const unsigned short* An = smem + ((t_ + 1) & 3) * BUF;               \
        _Pragma("unroll")                                                     \
        for (int j = 0; j < 4; ++j)                                           \
            NAB[j] = *(const bf16x8*)&An[(wm + 64 + j * 16) * 32 + loff];     \
    }                                                                         \
  }

__global__ __launch_bounds__(512, 2) void gemm_kernel(
    const unsigned short* __restrict__ A,
    const unsigned short* __restrict__ Bp,
    const float* __restrict__ bias,
    float* __restrict__ C, int M)
{
    constexpr int K = 1024, N = 1024;
    constexpr int BUF = 16384;                    // shorts per buffer: A 8192 + B 8192
    __shared__ __align__(16) unsigned short smem[4 * BUF];   // 128 KiB

    const int tid  = threadIdx.x;
    const int lane = tid & 63;
    const int wave = tid >> 6;
    const int wm   = (wave >> 2) * 128;           // 2 M-wave-groups
    const int wn   = (wave & 3) * 64;             // 4 N-wave-groups

    // T1: XCD-aware block swizzle (nwg = 512, divisible by 8 -> bijective)
    const int nwg = gridDim.x;
    int wg = blockIdx.x;
    if ((nwg & 7) == 0) wg = (wg & 7) * (nwg >> 3) + (wg >> 3);
    const int bm = (wg >> 2) * 256;               // n fastest -> A-panel L2 reuse
    const int bn = (wg & 3) * 256;

    // ---- staging addressing (T2: linear LDS dest + pre-swizzled global src) ----
    const int qsrc = (((lane & 3) ^ ((lane >> 3) & 3))) * 8;  // element offset
    const int rA0  = (wave * 2) * 16 + (lane >> 2);
    const unsigned short* gA0 = A  + (size_t)(bm + rA0) * K + qsrc;
    const unsigned short* gA1 = A  + (size_t)(bm + rA0 + 16) * K + qsrc;
    const unsigned short* gB0 = Bp + (size_t)(bn + rA0) * K + qsrc;
    const unsigned short* gB1 = Bp + (size_t)(bn + rA0 + 16) * K + qsrc;
    const int sA0 = (wave * 2) * 512 + lane * 8;  // shorts within buf (linear)
    const int sA1 = sA0 + 512;
    const int sB0 = 8192 + sA0;
    const int sB1 = 8192 + sA1;

    // ---- fragment read offset (swizzled): 2-way bank aliasing = free ----
    const int fr   = lane & 15;
    const int quad = lane >> 4;
    const int loff = fr * 32 + ((quad ^ ((fr >> 1) & 3)) * 8);

    f32x4 acc[8][4] = {};

    // prologue: stage K-tiles 0,1,2 (12 loads/thread in flight)
#pragma unroll
    for (int kt = 0; kt < 3; ++kt) {
        unsigned short* sb = smem + kt * BUF;
        gld16(gA0 + kt * 32, sb + sA0);
        gld16(gA1 + kt * 32, sb + sA1);
        gld16(gB0 + kt * 32, sb + sB0);
        gld16(gB1 + kt * 32, sb + sB1);
    }
    asm volatile("s_waitcnt vmcnt(8)" ::: "memory");  // own tile-0 loads landed
    __builtin_amdgcn_s_barrier();                     // all waves' tile 0 in LDS

    bf16x8 afA0[4], afB0[4], bfr0[4], afA1[4], afB1[4], bfr1[4];
    {   // initial fragments: ALL of tile 0
        const unsigned short* A0 = smem;
        const unsigned short* B0 = smem + 8192;
#pragma unroll
        for (int j = 0; j < 4; ++j)
            bfr0[j] = *(const bf16x8*)&B0[(wn + j * 16) * 32 + loff];
#pragma unroll
        for (int j = 0; j < 4; ++j)
            afA0[j] = *(const bf16x8*)&A0[(wm + j * 16) * 32 + loff];
#pragma unroll
        for (int j = 0; j < 4; ++j)
            afB0[j] = *(const bf16x8*)&A0[(wm + 64 + j * 16) * 32 + loff];
    }

    for (int t = 0; t < 32; t += 2) {
        GEMM_ITER(t,     afA0, afB0, bfr0, afA1, afB1, bfr1)
        GEMM_ITER(t + 1, afA1, afB1, bfr1, afA0, afB0, bfr0)
    }

    // ---- epilogue: vectorized per-wave LDS transpose -> full 128B lines ----
    // Swapped-operand C/D layout: acc[mi][ni] reg r = C[wm+mi*16+fr][wn+ni*16+quad*4+r].
    // ds_write_b128 (2-way, free) -> ds_read_b128 (2-way) -> 256B/row stores.
    float* tb = (float*)smem + wave * 1088;   // 16 rows x 68 floats, per-wave private
    const int q4 = quad * 4;
    const float4 bvT = *(const float4*)&bias[bn + wn + fr * 4];
#pragma unroll
    for (int mi = 0; mi < 8; ++mi) {
#pragma unroll
        for (int ni = 0; ni < 4; ++ni)
            *(float4*)&tb[fr * 68 + ni * 16 + q4] = *(const float4*)&acc[mi][ni];
        // same-wave LDS: in-order pipe + compiler lgkmcnt waits; no barrier
#pragma unroll
        for (int j = 0; j < 4; ++j) {
            const int row = j * 4 + quad;
            const float4 v = *(const float4*)&tb[row * 68 + fr * 4];
            float4 o;
            o.x = v.x + bvT.x; o.y = v.y + bvT.y;
            o.z = v.z + bvT.z; o.w = v.w + bvT.w;
            *(float4*)&C[(size_t)(bm + wm + mi * 16 + row) * N + bn + wn + fr * 4] = o;
        }
    }
}

extern "C" void kernel_launch(void* const* d_in, const int* in_sizes, int n_in,
                              void* d_out, int out_size, void* d_ws, size_t ws_size,
                              hipStream_t stream)
{
    const float* x     = (const float*)d_in[0];
    const int*   cid   = (const int*)d_in[1];
    const float* gamma = (const float*)d_in[2];
    const float* beta  = (const float*)d_in[3];
    const float* scale = (const float*)d_in[4];
    const float* W     = (const float*)d_in[5];
    const float* bias  = (const float*)d_in[6];
    float* out = (float*)d_out;

    const int M = in_sizes[0] / DM;                        // 32768 tokens
    unsigned short* yb = (unsigned short*)d_ws;            // M*1024 bf16 = 64 MB
    unsigned short* Wb = yb + (size_t)M * DM;              // 1024*1024 bf16 = 2 MB

    // one wave per unit: (M + DM) units, 4 waves per 256-thread block
    ln_w_kernel<<<(M + DM) / 4, 256, 0, stream>>>(x, cid, gamma, beta, scale, W, yb, Wb, M);
    gemm_kernel<<<dim3((M / 256) * 4), 512, 0, stream>>>(yb, Wb, bias, out, M);
}